// Round 3
// baseline (233.065 us; speedup 1.0000x reference)
//
#include <hip/hip_runtime.h>
#include <math.h>

// Problem constants (from reference)
constexpr int L     = 2048;   // series length
constexpr int NH    = 96;     // forecast horizon / W cols
constexpr int MLEN  = 150;    // AR2 fit window
constexpr int NAR   = 148;    // number of AR2 regression terms
constexpr float LAM    = 0.001f;
constexpr float CLIP_K = 4.0f;

constexpr int NWAVE = 4;          // K-split factor (waves per block)
constexpr int KPW   = L / NWAVE;  // 512 K per wave
constexpr int STEPS = KPW / 32;   // 16 MFMA K-steps per wave

typedef __attribute__((ext_vector_type(8))) short short8;   // 8 bf16 MFMA A/B frag
typedef __attribute__((ext_vector_type(4))) float floatx4;  // MFMA C/D frag

// fp32 -> bf16 round-to-nearest-even
__device__ inline short f2bf(float f) {
    union { float f; unsigned u; } v; v.f = f;
    unsigned r = v.u + 0x7FFFu + ((v.u >> 16) & 1u);
    return (short)(r >> 16);
}

// Pre-kernel: Wt[n][k] = bf16(W[k][n]); W is 768 KB -> L2-resident gather.
__global__ __launch_bounds__(256) void wt_kernel(
    const float* __restrict__ W, short* __restrict__ Wt)
{
    int idx = blockIdx.x * 256 + threadIdx.x;   // n*2048 + k
    int n = idx >> 11;
    int k = idx & 2047;
    Wt[idx] = f2bf(W[k * NH + n]);
}

// Main kernel: 256 threads = 4 waves per 16-row tile; wave w streams K-chunk
// [w*512, (w+1)*512). Per K=32 step: A from global x (fp32->bf16 in-reg),
// B from bf16 Wt, 6x mfma_f32_16x16x32_bf16. Partial acc + row stats reduce
// via LDS; wave 0 runs AR2 fit, recurrence, clip, store.
// MFMA layouts: A[m=lane&15][k=quad*8+j]; B[k=quad*8+j][n=lane&15];
// D col=lane&15, row=quad*4+reg.
__global__ __launch_bounds__(256, 4) void gemm_ar2_kernel(
    const float* __restrict__ x, const short* __restrict__ Wt,
    float* __restrict__ out)
{
    __shared__ float accP[NWAVE - 1][64][24];   // partial accumulators (waves 1..3)
    __shared__ float sumP[NWAVE][16], sumsqP[NWAVE][16];
    __shared__ float Ys[16][NH + 1];            // +1 pad (stride-97 writes)

    const int t    = threadIdx.x;
    const int lane = t & 63;
    const int wv   = t >> 6;           // wave id = K-chunk id
    const int m    = lane & 15;        // tile row (A) / tile col (B,D)
    const int quad = lane >> 4;        // k-sub-chunk selector
    const int row0 = blockIdx.x * 16;

    const float* arow  = x  + (size_t)(row0 + m) * L + wv * KPW + quad * 8;
    const short* wbase = Wt + (size_t)m * L        + wv * KPW + quad * 8;

    floatx4 acc[6];
    #pragma unroll
    for (int j = 0; j < 6; ++j) acc[j] = floatx4{0.f, 0.f, 0.f, 0.f};

    float sum = 0.f, sumsq = 0.f;

    // Software pipeline: A prefetch depth 2, B depth 1.
    float4 a0_c = *(const float4*)(arow + 0);
    float4 a1_c = *(const float4*)(arow + 4);
    float4 a0_n = *(const float4*)(arow + 32);
    float4 a1_n = *(const float4*)(arow + 36);
    short8 b_c[6];
    #pragma unroll
    for (int j = 0; j < 6; ++j) b_c[j] = *(const short8*)(wbase + j * 16 * L);

    for (int step = 0; step < STEPS; ++step) {
        int k2 = (step + 2 < STEPS) ? (step + 2) * 32 : step * 32;
        int k1 = (step + 1 < STEPS) ? (step + 1) * 32 : step * 32;
        float4 a0_p = *(const float4*)(arow + k2);
        float4 a1_p = *(const float4*)(arow + k2 + 4);
        short8 b_n[6];
        #pragma unroll
        for (int j = 0; j < 6; ++j)
            b_n[j] = *(const short8*)(wbase + j * 16 * L + k1);

        // per-row stats on current A (each lane sees only row m)
        sum   += ((a0_c.x + a0_c.y) + (a0_c.z + a0_c.w))
               + ((a1_c.x + a1_c.y) + (a1_c.z + a1_c.w));
        sumsq = fmaf(a0_c.x, a0_c.x, sumsq); sumsq = fmaf(a0_c.y, a0_c.y, sumsq);
        sumsq = fmaf(a0_c.z, a0_c.z, sumsq); sumsq = fmaf(a0_c.w, a0_c.w, sumsq);
        sumsq = fmaf(a1_c.x, a1_c.x, sumsq); sumsq = fmaf(a1_c.y, a1_c.y, sumsq);
        sumsq = fmaf(a1_c.z, a1_c.z, sumsq); sumsq = fmaf(a1_c.w, a1_c.w, sumsq);

        short8 af;
        af[0] = f2bf(a0_c.x); af[1] = f2bf(a0_c.y);
        af[2] = f2bf(a0_c.z); af[3] = f2bf(a0_c.w);
        af[4] = f2bf(a1_c.x); af[5] = f2bf(a1_c.y);
        af[6] = f2bf(a1_c.z); af[7] = f2bf(a1_c.w);

        #pragma unroll
        for (int j = 0; j < 6; ++j)
            acc[j] = __builtin_amdgcn_mfma_f32_16x16x32_bf16(af, b_c[j], acc[j], 0, 0, 0);

        a0_c = a0_n; a1_c = a1_n;
        a0_n = a0_p; a1_n = a1_p;
        #pragma unroll
        for (int j = 0; j < 6; ++j) b_c[j] = b_n[j];
    }

    // --- within-wave stats reduce over the 4 quads sharing row m ---
    sum   += __shfl_xor(sum,   16); sum   += __shfl_xor(sum,   32);
    sumsq += __shfl_xor(sumsq, 16); sumsq += __shfl_xor(sumsq, 32);
    if (quad == 0) { sumP[wv][m] = sum; sumsqP[wv][m] = sumsq; }

    // --- waves 1..3 dump partial accumulators ---
    if (wv > 0) {
        #pragma unroll
        for (int j = 0; j < 6; ++j)
            #pragma unroll
            for (int r = 0; r < 4; ++r)
                accP[wv - 1][lane][j * 4 + r] = acc[j][r];
    }
    __syncthreads();

    if (wv != 0) return;               // wave 0 does the rest

    // --- combine partial accumulators ---
    #pragma unroll
    for (int w = 0; w < NWAVE - 1; ++w)
        #pragma unroll
        for (int j = 0; j < 6; ++j)
            #pragma unroll
            for (int r = 0; r < 4; ++r)
                acc[j][r] += accP[w][lane][j * 4 + r];

    // --- combine row stats (LDS broadcast: 4 lanes share each addr) ---
    float sumT   = sumP[0][m]   + sumP[1][m]   + sumP[2][m]   + sumP[3][m];
    float sumsqT = sumsqP[0][m] + sumsqP[1][m] + sumsqP[2][m] + sumsqP[3][m];

    // --- AR2 normal-equation sums over the last-150 tail (cache-hot) ---
    const float* ytail = x + (size_t)(row0 + m) * L + (L - MLEN);
    float A11 = 0.f, A22 = 0.f, A12 = 0.f, b1 = 0.f, b2 = 0.f;
    for (int i = quad; i < NAR; i += 4) {
        float p2v = ytail[i];
        float p1v = ytail[i + 1];
        float Yv  = ytail[i + 2];
        A11 = fmaf(p1v, p1v, A11);
        A22 = fmaf(p2v, p2v, A22);
        A12 = fmaf(p1v, p2v, A12);
        b1  = fmaf(p1v, Yv,  b1);
        b2  = fmaf(p2v, Yv,  b2);
    }
    A11 += __shfl_xor(A11, 16); A11 += __shfl_xor(A11, 32);
    A22 += __shfl_xor(A22, 16); A22 += __shfl_xor(A22, 32);
    A12 += __shfl_xor(A12, 16); A12 += __shfl_xor(A12, 32);
    b1  += __shfl_xor(b1,  16); b1  += __shfl_xor(b1,  32);
    b2  += __shfl_xor(b2,  16); b2  += __shfl_xor(b2,  32);

    float lo = 0.f, hi = 0.f;
    if (quad == 0) {                   // lanes 0..15: row m
        A11 += LAM; A22 += LAM;
        float det = A11 * A22 - A12 * A12;
        float a1c = (b1 * A22 - b2 * A12) / det;
        float a2c = (A11 * b2 - A12 * b1) / det;

        float last = ytail[MLEN - 1];
        float y1 = last;
        float y2 = ytail[MLEN - 2];
        for (int n = 0; n < NH; ++n) {
            float yn = a1c * y1 + a2c * y2;
            Ys[m][n] = yn;
            y2 = y1; y1 = yn;
        }
        float var  = (sumsqT - sumT * sumT * (1.0f / L)) * (1.0f / (L - 1));
        float hstd = fmaxf(sqrtf(fmaxf(var, 0.f)), 1e-6f);
        lo = last - CLIP_K * hstd;
        hi = last + CLIP_K * hstd;
    }
    // single-wave LDS write->read ordering
    asm volatile("s_waitcnt lgkmcnt(0)" ::: "memory");

    // --- epilogue: out = clip(Yb + d_hat, lo, hi) ---
    #pragma unroll
    for (int reg = 0; reg < 4; ++reg) {
        int r = quad * 4 + reg;
        float rlo = __shfl(lo, r);
        float rhi = __shfl(hi, r);
        #pragma unroll
        for (int j = 0; j < 6; ++j) {
            int c = 16 * j + m;
            float v = acc[j][reg] + Ys[r][c];
            v = fminf(fmaxf(v, rlo), rhi);
            out[(size_t)(row0 + r) * NH + c] = v;
        }
    }
}

extern "C" void kernel_launch(void* const* d_in, const int* in_sizes, int n_in,
                              void* d_out, int out_size, void* d_ws, size_t ws_size,
                              hipStream_t stream) {
    const float* x = (const float*)d_in[0];   // (32,512,2048) fp32
    const float* W = (const float*)d_in[1];   // (2048,96) fp32
    float* out = (float*)d_out;               // (32,512,96) fp32
    short* Wt  = (short*)d_ws;                // 96*2048 bf16 = 384 KB scratch

    wt_kernel<<<dim3((NH * L) / 256), dim3(256), 0, stream>>>(W, Wt);

    const int rows = 32 * 512;                // 16384
    gemm_ar2_kernel<<<dim3(rows / 16), dim3(256), 0, stream>>>(x, Wt, out);
}